// Round 11
// baseline (346.470 us; speedup 1.0000x reference)
//
#include <hip/hip_runtime.h>
#include <hip/hip_bf16.h>

// Problem constants
#define B_SZ   4096
#define OBS_N  128
#define HID    512

// S-MAJOR q rows: r = s*4096 + b. Fused kernel: block = 64 rows (one s, 64 b's),
// 512 threads (8 waves), 3 hidden layers chained through a 64KB LDS buffer
// (XOR-swizzled chunks). Layers compute D = W·hs (out x batch).
// W1/W2/W3 (and v) MFMA-TILED; W frags register-prefetched one kc ahead.
// Phase 0 is MFMA with acc initialized from FRAGMENT-TILED fp32 P (coalesced
// 1KB loads). adv output staged through LDS for coalesced float2 stores.
// 3 dispatches: prep | P | fused.

typedef __bf16 bf16x8_t __attribute__((ext_vector_type(8)));
typedef float  f32x4_t  __attribute__((ext_vector_type(4)));

__device__ inline float fast_tanh(float x) {
    // tanh(x) = 1 - 2/(e^{2x}+1); v_exp_f32 computes 2^x, clamp-free, inf-safe.
    float e = __builtin_amdgcn_exp2f(x * 2.885390081777927f);
    return fmaf(-2.f, __builtin_amdgcn_rcpf(e + 1.f), 1.f);
}

__device__ inline void gld_lds16(const void* g, void* l) {
    __builtin_amdgcn_global_load_lds(
        (const __attribute__((address_space(1))) void*)g,
        (__attribute__((address_space(3))) void*)l, 16, 0, 0);
}

// hs element (row, col): chunk c = col/8, phys = (c&~7)|((c^(row&7))&7),
// offset row*512 + phys*8 + col%8.
__device__ inline int hs_off(int row, int col) {
    int c = col >> 3;
    int phys = (c & ~7) | ((c ^ (row & 7)) & 7);
    return row * 512 + phys * 8 + (col & 7);
}

// ---------------- combined prep ----------------
__global__ __launch_bounds__(256) void prep_kernel(
    const float* __restrict__ obs, const int* __restrict__ category,
    const float* __restrict__ qw0, const float* __restrict__ qb0,
    const float* __restrict__ qw1, const float* __restrict__ qw2,
    const float* __restrict__ qw3,
    const float* __restrict__ vw0, const float* __restrict__ vb0,
    const float* __restrict__ vw1, const float* __restrict__ vw2,
    __hip_bfloat16* __restrict__ obs_bf,
    __hip_bfloat16* __restrict__ w0t, __hip_bfloat16* __restrict__ w1t,
    __hip_bfloat16* __restrict__ w2t, __hip_bfloat16* __restrict__ w3t,
    __hip_bfloat16* __restrict__ vw0t, __hip_bfloat16* __restrict__ vw1t,
    __hip_bfloat16* __restrict__ vw2t,
    __hip_bfloat16* __restrict__ w0aug, __hip_bfloat16* __restrict__ vw0aug,
    __hip_bfloat16* __restrict__ acts_bf, float* __restrict__ nbias)
{
    const int bid = blockIdx.x, tid = threadIdx.x;
    if (bid < 2048) {
        int i = bid * 256 + tid;
        obs_bf[i] = __float2bfloat16(obs[i]);
    } else if (bid < 2560) {   // (512,128) transposes (row-major, for gemm_dual)
        const float* src = (bid < 2304) ? qw0 : vw0;
        __hip_bfloat16* dst = (bid < 2304) ? w0t : vw0t;
        int idx = ((bid - 2048) & 255) * 256 + tid;
        int n = idx >> 7, k = idx & 127;
        dst[idx] = __float2bfloat16(src[k * 512 + n]);
    } else if (bid < 7680) {   // (512,512) -> MFMA-tiled
        int job = (bid - 2560) >> 10;            // 0..4
        const float* srcs[5] = {qw1, qw2, qw3, vw1, vw2};
        __hip_bfloat16* dsts[5] = {w1t, w2t, w3t, vw1t, vw2t};
        int idx = ((bid - 2560) & 1023) * 256 + tid;   // 0..262143
        int e    = idx & 7;
        int lane = (idx >> 3) & 63;
        int kc   = (idx >> 9) & 15;
        int tile = idx >> 13;
        int k = kc * 32 + (lane >> 4) * 8 + e;
        int n = tile * 16 + (lane & 15);
        dsts[job][idx] = __float2bfloat16(srcs[job][k * 512 + n]);
    } else if (bid < 11776) {  // acts_bf table, s-major bf16: acts_bf[(s*4096+b)*8+d]
        int t = (bid - 7680) * 256 + tid;
        int d = t & 7;
        int r = t >> 3;
        int b = r & 4095, s = r >> 12;
        int U = (s >> 3) + ((d < (s & 7)) ? 1 : 0);
        float a = 0.f;
        if (U > 0) {
            float w = 0.125f, cum = 0.f;
            for (int j = 0; j < U; ++j) {
                cum += (float)category[b * 32 + j * 8 + d] * w;
                if (j == U - 1) a = -1.f + cum + 0.5f * w;
                w *= 0.0625f;
            }
        }
        acts_bf[t] = __float2bfloat16(a);
    } else if (bid < 11904) {  // w0aug + vw0aug (64 blocks each)
        int sub = bid - 11776;
        bool isv = sub >= 64;
        int idx = (sub & 63) * 256 + tid;   // 0..16383
        int e    = idx & 7;
        int lane = (idx >> 3) & 63;
        int tile = idx >> 9;
        int k = (lane >> 4) * 8 + e;
        int n = tile * 16 + (lane & 15);
        float v = 0.f;
        if (!isv) {
            if (k < 8) v = qw0[(128 + k) * 512 + n];
            else if (k == 8) v = qb0[n];
            w0aug[idx] = __float2bfloat16(v);
        } else {
            if (k == 8) v = vb0[n];
            vw0aug[idx] = __float2bfloat16(v);
        }
    } else {                   // nbias = 0
        int i = (bid - 11904) * 256 + tid;
        nbias[i] = 0.f;
    }
}

// ---------------- dual-job GEMM (P dispatch) ----------------
// epi==3: store fp32 FRAGMENT-TILED for the fused kernel:
// idx = (((m>>6)*8 + (col>>6))*16 + (brow>>4)*4 + ((col>>4)&3))*256
//       + ((col>>2)&3)*64 + (brow&15)*4 + (col&3)
__global__ __launch_bounds__(256) void gemm_dual(
    const __hip_bfloat16* __restrict__ A0, const __hip_bfloat16* __restrict__ B0,
    const float* __restrict__ bias0, void* __restrict__ C0, int K0, int epi0, int nb0,
    const __hip_bfloat16* __restrict__ A1, const __hip_bfloat16* __restrict__ B1,
    const float* __restrict__ bias1, void* __restrict__ C1, int K1, int epi1)
{
    __shared__ __hip_bfloat16 As[128 * 32];
    __shared__ __hip_bfloat16 Bs[128 * 32];

    const __hip_bfloat16 *A, *Bt;
    const float* bias;
    void* Cout;
    int K, epi, tb;
    if ((int)blockIdx.x < nb0) {
        A = A0; Bt = B0; bias = bias0; Cout = C0; K = K0; epi = epi0; tb = blockIdx.x;
    } else {
        A = A1; Bt = B1; bias = bias1; Cout = C1; K = K1; epi = epi1; tb = blockIdx.x - nb0;
    }
    const long m0 = (long)(tb >> 2) * 128;
    const int  n0 = (tb & 3) * 128;

    const int tid  = threadIdx.x;
    const int wave = tid >> 6, lane = tid & 63;
    const int quad = lane >> 4, t = lane & 15;
    const int wr = wave >> 1, wc = wave & 1;

    f32x4_t acc[4][4] = {};

    const int lrow  = lane >> 2;
    const int lkoff = (((lane & 3) + (lane >> 3)) & 3) * 8;

    const __hip_bfloat16* Ag0 = A  + (m0 + wave * 32 +      lrow) * (long)K + lkoff;
    const __hip_bfloat16* Ag1 = A  + (m0 + wave * 32 + 16 + lrow) * (long)K + lkoff;
    const __hip_bfloat16* Bg0 = Bt + (long)(n0 + wave * 32 +      lrow) * K + lkoff;
    const __hip_bfloat16* Bg1 = Bt + (long)(n0 + wave * 32 + 16 + lrow) * K + lkoff;
    __hip_bfloat16* AsB0 = &As[(wave * 32) * 32];
    __hip_bfloat16* AsB1 = &As[(wave * 32 + 16) * 32];
    __hip_bfloat16* BsB0 = &Bs[(wave * 32) * 32];
    __hip_bfloat16* BsB1 = &Bs[(wave * 32 + 16) * 32];

    const int slot = ((quad - (t >> 1)) & 3) * 8;

    for (int k0 = 0; k0 < K; k0 += 32) {
        gld_lds16(Ag0 + k0, AsB0);
        gld_lds16(Ag1 + k0, AsB1);
        gld_lds16(Bg0 + k0, BsB0);
        gld_lds16(Bg1 + k0, BsB1);
        __syncthreads();
        bf16x8_t af[4], bfr[4];
        #pragma unroll
        for (int i = 0; i < 4; ++i)
            af[i] = *(const bf16x8_t*)&As[(wr * 64 + i * 16 + t) * 32 + slot];
        #pragma unroll
        for (int j = 0; j < 4; ++j)
            bfr[j] = *(const bf16x8_t*)&Bs[(wc * 64 + j * 16 + t) * 32 + slot];
        #pragma unroll
        for (int i = 0; i < 4; ++i)
            #pragma unroll
            for (int j = 0; j < 4; ++j)
                acc[i][j] = __builtin_amdgcn_mfma_f32_16x16x32_bf16(af[i], bfr[j], acc[i][j], 0, 0, 0);
        __syncthreads();
    }

    #pragma unroll
    for (int i = 0; i < 4; ++i) {
        const long rbase = m0 + wr * 64 + i * 16 + quad * 4;
        #pragma unroll
        for (int j = 0; j < 4; ++j) {
            const int col = n0 + wc * 64 + j * 16 + t;
            #pragma unroll
            for (int r = 0; r < 4; ++r) {
                float v = acc[i][j][r];
                if (epi == 1) {
                    v = fast_tanh(v + bias[col]);
                    ((__hip_bfloat16*)Cout)[(rbase + r) * 512 + col] = __float2bfloat16(v);
                } else if (epi == 2) {
                    ((__hip_bfloat16*)Cout)[(rbase + r) * 512 + col] = __float2bfloat16(v);
                } else if (epi == 3) {
                    const long m = rbase + r;
                    const int brow = (int)(m & 63);
                    const long idx =
                        ((((m >> 6) * 8 + (col >> 6)) * 16 + (brow >> 4) * 4 + ((col >> 4) & 3)) * 256)
                        + ((col >> 2) & 3) * 64 + (brow & 15) * 4 + (col & 3);
                    ((float*)Cout)[idx] = v;
                } else {
                    ((float*)Cout)[(rbase + r) * 512 + col] = v;
                }
            }
        }
    }
}

// ---------------- epilogue: tanh(acc) -> hs (XOR-swizzled), optional bias ----------------
__device__ inline void epi_store(
    __hip_bfloat16* hs, f32x4_t acc[4][4], const float* bias,
    int n0w, int quad, int t)
{
    #pragma unroll
    for (int j = 0; j < 4; ++j) {
        const int oc0 = n0w + j * 16 + quad * 4;     // 4 consecutive out cols
        float4 bl = {0.f, 0.f, 0.f, 0.f};
        if (bias) bl = *(const float4*)&bias[oc0];
        const int cbase = oc0 >> 3;
        const int sub = (quad & 1) * 4;
        #pragma unroll
        for (int rt = 0; rt < 4; ++rt) {
            const int row = rt * 16 + t;
            union { __hip_bfloat16 b[4]; uint2 v; } o;
            o.b[0] = __float2bfloat16(fast_tanh(acc[rt][j][0] + bl.x));
            o.b[1] = __float2bfloat16(fast_tanh(acc[rt][j][1] + bl.y));
            o.b[2] = __float2bfloat16(fast_tanh(acc[rt][j][2] + bl.z));
            o.b[3] = __float2bfloat16(fast_tanh(acc[rt][j][3] + bl.w));
            const int phys = (cbase & ~7) | ((cbase ^ (row & 7)) & 7);
            *(uint2*)&hs[row * 512 + phys * 8 + sub] = o.v;
        }
    }
}

// ---------------- fused MLP layer: hs(64x512) = tanh(hs @ W^T + bias) ----------------
__device__ inline void mfma_layer(
    __hip_bfloat16* hs, const __hip_bfloat16* __restrict__ Wt,
    const float* __restrict__ bias, int w, int lane)
{
    const int quad = lane >> 4, t = lane & 15;
    const int n0w = w * 64;
    const __hip_bfloat16* Wl = Wt + ((size_t)(w * 4) * 16 * 64 + lane) * 8;
    f32x4_t acc[4][4] = {};   // [rt = batch tile][j = out tile]
    bf16x8_t wc[4], wn[4], ac[4];
    #pragma unroll
    for (int j = 0; j < 4; ++j)
        wc[j] = *(const bf16x8_t*)(Wl + (size_t)(j * 16) * 512);

    #pragma unroll 4
    for (int kc = 0; kc < 16; ++kc) {
        const int craw = kc * 4 + quad;
        const int phys = (craw & ~7) | ((craw ^ (t & 7)) & 7);
        #pragma unroll
        for (int rt = 0; rt < 4; ++rt)
            ac[rt] = *(const bf16x8_t*)&hs[(rt * 16 + t) * 512 + phys * 8];
        if (kc < 15) {
            #pragma unroll
            for (int j = 0; j < 4; ++j)
                wn[j] = *(const bf16x8_t*)(Wl + (size_t)(j * 16 + kc + 1) * 512);
        }
        #pragma unroll
        for (int j = 0; j < 4; ++j)
            #pragma unroll
            for (int rt = 0; rt < 4; ++rt)
                acc[rt][j] = __builtin_amdgcn_mfma_f32_16x16x32_bf16(wc[j], ac[rt], acc[rt][j], 0, 0, 0);
        #pragma unroll
        for (int j = 0; j < 4; ++j) wc[j] = wn[j];
    }
    __syncthreads();   // all reads of hs complete
    epi_store(hs, acc, bias, n0w, quad, t);
    __syncthreads();   // hs now holds the layer output
}

// ---------------- fused MLP kernel: q-blocks [0,2048), v-blocks [2048,2112) ----------------
__global__ __launch_bounds__(512, 4) void fused_kernel(
    const float* __restrict__ p,               // fragment-tiled fp32 = obs@W0a
    const float* __restrict__ pv,              // fragment-tiled fp32 = obs@vW0
    const __hip_bfloat16* __restrict__ acts_bf,// (131072,8) bf16 s-major
    const __hip_bfloat16* __restrict__ w0aug,  // tiled aug (32 tiles)
    const __hip_bfloat16* __restrict__ vw0aug,
    const __hip_bfloat16* __restrict__ w1t, const float* __restrict__ qb1,
    const __hip_bfloat16* __restrict__ w2t, const float* __restrict__ qb2,
    const __hip_bfloat16* __restrict__ w3t, const float* __restrict__ qb3,
    float* __restrict__ advout,
    const __hip_bfloat16* __restrict__ vw1t, const float* __restrict__ vb1,
    const __hip_bfloat16* __restrict__ vw2t, const float* __restrict__ vb2,
    const float* __restrict__ vw3, const float* __restrict__ vb3,
    float* __restrict__ vout)
{
    __shared__ __hip_bfloat16 hs[64 * 512];   // 64 KB
    const int bid = blockIdx.x;
    const int tid = threadIdx.x;
    const int w = tid >> 6, lane = tid & 63;
    const int quad = lane >> 4, t = lane & 15;
    const bool is_q = bid < 2048;
    const int s  = is_q ? (bid >> 6) : 0;
    const int mb = is_q ? (bid & 63) : (bid - 2048);
    const int n0w = w * 64;

    // ---- phase 0 as MFMA: D = W0aug·[acts;1] + p (acc init from tiled fp32 P) ----
    {
        const float* Pt = (is_q ? p : pv) + (((size_t)mb * 8 + w) * 16) * 256 + lane * 4;
        const __hip_bfloat16* W0 = is_q ? w0aug : vw0aug;
        f32x4_t acc[4][4];
        #pragma unroll
        for (int rt = 0; rt < 4; ++rt)
            #pragma unroll
            for (int j = 0; j < 4; ++j)
                acc[rt][j] = *(const f32x4_t*)(Pt + (rt * 4 + j) * 256);
        // B-frags: quad0 = acts (q only), quad1 = e0 1.0, else 0
        bf16x8_t bfrag[4];
        #pragma unroll
        for (int rt = 0; rt < 4; ++rt) {
            union { bf16x8_t vec; unsigned short u[8]; } bu;
            #pragma unroll
            for (int i = 0; i < 8; ++i) bu.u[i] = 0;
            if (quad == 1) bu.u[0] = 0x3F80;   // bf16 1.0
            if (is_q && quad == 0) {
                const long r = (long)s * 4096 + mb * 64 + rt * 16 + t;
                bu.vec = *(const bf16x8_t*)&acts_bf[r * 8];
            }
            bfrag[rt] = bu.vec;
        }
        bf16x8_t wq[4];
        #pragma unroll
        for (int j = 0; j < 4; ++j)
            wq[j] = *(const bf16x8_t*)(W0 + ((size_t)(w * 4 + j) * 64 + lane) * 8);
        #pragma unroll
        for (int j = 0; j < 4; ++j)
            #pragma unroll
            for (int rt = 0; rt < 4; ++rt)
                acc[rt][j] = __builtin_amdgcn_mfma_f32_16x16x32_bf16(wq[j], bfrag[rt], acc[rt][j], 0, 0, 0);
        epi_store(hs, acc, nullptr, n0w, quad, t);
    }
    __syncthreads();

    // ---- layers 1 and 2 ----
    mfma_layer(hs, is_q ? w1t : vw1t, is_q ? qb1 : vb1, w, lane);
    mfma_layer(hs, is_q ? w2t : vw2t, is_q ? qb2 : vb2, w, lane);

    // ---- layer 3 ----
    if (is_q) {
        // diag slice: 64 rows x 16 cols; waves 0..3 compute, output staged in LDS
        f32x4_t acc = {};
        if (w < 4) {
            const __hip_bfloat16* W3l = w3t + ((size_t)s * 16 * 64 + (size_t)lane) * 8;
            #pragma unroll 4
            for (int kc = 0; kc < 16; ++kc) {
                const int craw = kc * 4 + quad;
                const int phys = (craw & ~7) | ((craw ^ (t & 7)) & 7);
                bf16x8_t a = *(const bf16x8_t*)&hs[(w * 16 + t) * 512 + phys * 8];
                bf16x8_t bq = *(const bf16x8_t*)(W3l + (size_t)kc * 512);
                acc = __builtin_amdgcn_mfma_f32_16x16x32_bf16(a, bq, acc, 0, 0, 0);
            }
        }
        __syncthreads();   // L3 reads of hs done; hs reusable as fp32 staging
        float* hsf = (float*)hs;   // 64 rows x 16 cols
        if (w < 4) {
            const float bias3 = qb3[s * 16 + t];
            #pragma unroll
            for (int rr = 0; rr < 4; ++rr)
                hsf[(w * 16 + quad * 4 + rr) * 16 + t] = acc[rr] + bias3;
        }
        __syncthreads();
        // coalesced store: thread -> (row = tid>>3, colpair = tid&7), 64B/row
        const int row = tid >> 3, cp = tid & 7;
        float2 v2 = *(const float2*)&hsf[row * 16 + cp * 2];
        *(float2*)&advout[(size_t)(mb * 64 + row) * 512 + s * 16 + cp * 2] = v2;
    } else {
        // value head: row = tid>>3 (0..63), seg = tid&7 sums 64 elems
        const int row = tid >> 3, seg = tid & 7;
        float sum = 0.f;
        for (int k = seg * 64; k < seg * 64 + 64; ++k)
            sum += __bfloat162float(hs[hs_off(row, k)]) * vw3[k];
        sum += __shfl_xor(sum, 1);
        sum += __shfl_xor(sum, 2);
        sum += __shfl_xor(sum, 4);
        if (seg == 0) vout[mb * 64 + row] = sum + vb3[0];
    }
}

// ---------------- launch ----------------
extern "C" void kernel_launch(void* const* d_in, const int* in_sizes, int n_in,
                              void* d_out, int out_size, void* d_ws, size_t ws_size,
                              hipStream_t stream) {
    const float* obs      = (const float*)d_in[0];
    const int*   category = (const int*)d_in[1];
    const float* v_w0 = (const float*)d_in[2];
    const float* v_b0 = (const float*)d_in[3];
    const float* v_w1 = (const float*)d_in[4];
    const float* v_b1 = (const float*)d_in[5];
    const float* v_w2 = (const float*)d_in[6];
    const float* v_b2 = (const float*)d_in[7];
    const float* v_w3 = (const float*)d_in[8];
    const float* v_b3 = (const float*)d_in[9];
    const float* q_w0 = (const float*)d_in[10];
    const float* q_b0 = (const float*)d_in[11];
    const float* q_w1 = (const float*)d_in[12];
    const float* q_b1 = (const float*)d_in[13];
    const float* q_w2 = (const float*)d_in[14];
    const float* q_b2 = (const float*)d_in[15];
    const float* q_w3 = (const float*)d_in[16];
    const float* q_b3 = (const float*)d_in[17];

    char* ws = (char*)d_ws;
    __hip_bfloat16* obs_bf = (__hip_bfloat16*)(ws + 0);              // 1 MB
    __hip_bfloat16* w0t    = (__hip_bfloat16*)(ws + 1048576);        // (512,128) row-major
    __hip_bfloat16* vw0t   = (__hip_bfloat16*)(ws + 1179648);        // (512,128) row-major
    __hip_bfloat16* w1t    = (__hip_bfloat16*)(ws + 1310720);        // (512,512) tiled
    __hip_bfloat16* w2t    = (__hip_bfloat16*)(ws + 1835008);
    __hip_bfloat16* w3t    = (__hip_bfloat16*)(ws + 2359296);
    __hip_bfloat16* vw1t   = (__hip_bfloat16*)(ws + 2883584);
    __hip_bfloat16* vw2t   = (__hip_bfloat16*)(ws + 3407872);
    __hip_bfloat16* w0aug  = (__hip_bfloat16*)(ws + 3932160);        // 32 KB
    __hip_bfloat16* vw0aug = (__hip_bfloat16*)(ws + 3964928);        // 32 KB
    __hip_bfloat16* acts_bf= (__hip_bfloat16*)(ws + 3997696);        // (131072,8) bf16, 2 MB
    float*          p      = (float*)         (ws + 6094848);        // tiled fp32, 8 MB
    float*          pv     = (float*)         (ws + 14483456);       // tiled fp32, 8 MB

    float* out       = (float*)d_out;
    float* out_value = out;
    float* out_adv   = out + 4096;
    float* out_nbias = out + 4096 + (size_t)B_SZ * 512;

    // 1) all prep in one dispatch (incl. nbias zero)
    prep_kernel<<<12416, 256, 0, stream>>>(
        obs, category, q_w0, q_b0, q_w1, q_w2, q_w3, v_w0, v_b0, v_w1, v_w2,
        obs_bf, w0t, w1t, w2t, w3t, vw0t, vw1t, vw2t, w0aug, vw0aug,
        acts_bf, out_nbias);

    // 2) P: p = obs@W0a || pv = obs@vW0, fp32 fragment-tiled (epi=3)
    gemm_dual<<<256, 256, 0, stream>>>(
        obs_bf, w0t, nullptr, p, 128, 3, 128,
        obs_bf, vw0t, nullptr, pv, 128, 3);

    // 3) fused q+v MLP (2048 q-blocks + 64 v-blocks), 512 threads
    fused_kernel<<<2112, 512, 0, stream>>>(
        p, pv, acts_bf, w0aug, vw0aug, w1t, q_b1, w2t, q_b2, w3t, q_b3, out_adv,
        vw1t, v_b1, vw2t, v_b2, v_w3, v_b3, out_value);
}

// Round 12
// 269.194 us; speedup vs baseline: 1.2871x; 1.2871x over previous
//
#include <hip/hip_runtime.h>
#include <hip/hip_bf16.h>

// Problem constants
#define B_SZ   4096
#define OBS_N  128
#define HID    512

// S-MAJOR q rows: r = s*4096 + b. Fused kernel: block = 64 rows (one s, 64 b's),
// 512 threads (8 waves), 3 hidden layers chained through a 64KB LDS buffer
// (XOR-swizzled chunks). Layers compute D = W·hs (out x batch).
// W1/W2/W3 (and v) MFMA-TILED; W frags register-prefetched one kc ahead
// (unroll 2 — unroll 4 spills: R11 post-mortem, WRITE_SIZE 328 MB).
// Phase 0 is MFMA with acc initialized from FRAGMENT-TILED fp32 P (coalesced
// 1KB loads). adv output staged through LDS for coalesced float2 stores.
// 3 dispatches: prep | P | fused.

typedef __bf16 bf16x8_t __attribute__((ext_vector_type(8)));
typedef float  f32x4_t  __attribute__((ext_vector_type(4)));

__device__ inline float fast_tanh(float x) {
    // tanh(x) = 1 - 2/(e^{2x}+1); v_exp_f32 computes 2^x, clamp-free, inf-safe.
    float e = __builtin_amdgcn_exp2f(x * 2.885390081777927f);
    return fmaf(-2.f, __builtin_amdgcn_rcpf(e + 1.f), 1.f);
}

__device__ inline void gld_lds16(const void* g, void* l) {
    __builtin_amdgcn_global_load_lds(
        (const __attribute__((address_space(1))) void*)g,
        (__attribute__((address_space(3))) void*)l, 16, 0, 0);
}

// hs element (row, col): chunk c = col/8, phys = (c&~7)|((c^(row&7))&7),
// offset row*512 + phys*8 + col%8.
__device__ inline int hs_off(int row, int col) {
    int c = col >> 3;
    int phys = (c & ~7) | ((c ^ (row & 7)) & 7);
    return row * 512 + phys * 8 + (col & 7);
}

// ---------------- combined prep ----------------
__global__ __launch_bounds__(256) void prep_kernel(
    const float* __restrict__ obs, const int* __restrict__ category,
    const float* __restrict__ qw0, const float* __restrict__ qb0,
    const float* __restrict__ qw1, const float* __restrict__ qw2,
    const float* __restrict__ qw3,
    const float* __restrict__ vw0, const float* __restrict__ vb0,
    const float* __restrict__ vw1, const float* __restrict__ vw2,
    __hip_bfloat16* __restrict__ obs_bf,
    __hip_bfloat16* __restrict__ w0t, __hip_bfloat16* __restrict__ w1t,
    __hip_bfloat16* __restrict__ w2t, __hip_bfloat16* __restrict__ w3t,
    __hip_bfloat16* __restrict__ vw0t, __hip_bfloat16* __restrict__ vw1t,
    __hip_bfloat16* __restrict__ vw2t,
    __hip_bfloat16* __restrict__ w0aug, __hip_bfloat16* __restrict__ vw0aug,
    __hip_bfloat16* __restrict__ acts_bf, float* __restrict__ nbias)
{
    const int bid = blockIdx.x, tid = threadIdx.x;
    if (bid < 2048) {
        int i = bid * 256 + tid;
        obs_bf[i] = __float2bfloat16(obs[i]);
    } else if (bid < 2560) {   // (512,128) transposes (row-major, for gemm_dual)
        const float* src = (bid < 2304) ? qw0 : vw0;
        __hip_bfloat16* dst = (bid < 2304) ? w0t : vw0t;
        int idx = ((bid - 2048) & 255) * 256 + tid;
        int n = idx >> 7, k = idx & 127;
        dst[idx] = __float2bfloat16(src[k * 512 + n]);
    } else if (bid < 7680) {   // (512,512) -> MFMA-tiled
        int job = (bid - 2560) >> 10;            // 0..4
        const float* srcs[5] = {qw1, qw2, qw3, vw1, vw2};
        __hip_bfloat16* dsts[5] = {w1t, w2t, w3t, vw1t, vw2t};
        int idx = ((bid - 2560) & 1023) * 256 + tid;   // 0..262143
        int e    = idx & 7;
        int lane = (idx >> 3) & 63;
        int kc   = (idx >> 9) & 15;
        int tile = idx >> 13;
        int k = kc * 32 + (lane >> 4) * 8 + e;
        int n = tile * 16 + (lane & 15);
        dsts[job][idx] = __float2bfloat16(srcs[job][k * 512 + n]);
    } else if (bid < 11776) {  // acts_bf table, s-major bf16: acts_bf[(s*4096+b)*8+d]
        int t = (bid - 7680) * 256 + tid;
        int d = t & 7;
        int r = t >> 3;
        int b = r & 4095, s = r >> 12;
        int U = (s >> 3) + ((d < (s & 7)) ? 1 : 0);
        float a = 0.f;
        if (U > 0) {
            float w = 0.125f, cum = 0.f;
            for (int j = 0; j < U; ++j) {
                cum += (float)category[b * 32 + j * 8 + d] * w;
                if (j == U - 1) a = -1.f + cum + 0.5f * w;
                w *= 0.0625f;
            }
        }
        acts_bf[t] = __float2bfloat16(a);
    } else if (bid < 11904) {  // w0aug + vw0aug (64 blocks each)
        int sub = bid - 11776;
        bool isv = sub >= 64;
        int idx = (sub & 63) * 256 + tid;   // 0..16383
        int e    = idx & 7;
        int lane = (idx >> 3) & 63;
        int tile = idx >> 9;
        int k = (lane >> 4) * 8 + e;
        int n = tile * 16 + (lane & 15);
        float v = 0.f;
        if (!isv) {
            if (k < 8) v = qw0[(128 + k) * 512 + n];
            else if (k == 8) v = qb0[n];
            w0aug[idx] = __float2bfloat16(v);
        } else {
            if (k == 8) v = vb0[n];
            vw0aug[idx] = __float2bfloat16(v);
        }
    } else {                   // nbias = 0
        int i = (bid - 11904) * 256 + tid;
        nbias[i] = 0.f;
    }
}

// ---------------- dual-job GEMM (P dispatch) ----------------
// epi==3: store fp32 FRAGMENT-TILED for the fused kernel:
// idx = (((m>>6)*8 + (col>>6))*16 + (brow>>4)*4 + ((col>>4)&3))*256
//       + ((col>>2)&3)*64 + (brow&15)*4 + (col&3)
__global__ __launch_bounds__(256) void gemm_dual(
    const __hip_bfloat16* __restrict__ A0, const __hip_bfloat16* __restrict__ B0,
    const float* __restrict__ bias0, void* __restrict__ C0, int K0, int epi0, int nb0,
    const __hip_bfloat16* __restrict__ A1, const __hip_bfloat16* __restrict__ B1,
    const float* __restrict__ bias1, void* __restrict__ C1, int K1, int epi1)
{
    __shared__ __hip_bfloat16 As[128 * 32];
    __shared__ __hip_bfloat16 Bs[128 * 32];

    const __hip_bfloat16 *A, *Bt;
    const float* bias;
    void* Cout;
    int K, epi, tb;
    if ((int)blockIdx.x < nb0) {
        A = A0; Bt = B0; bias = bias0; Cout = C0; K = K0; epi = epi0; tb = blockIdx.x;
    } else {
        A = A1; Bt = B1; bias = bias1; Cout = C1; K = K1; epi = epi1; tb = blockIdx.x - nb0;
    }
    const long m0 = (long)(tb >> 2) * 128;
    const int  n0 = (tb & 3) * 128;

    const int tid  = threadIdx.x;
    const int wave = tid >> 6, lane = tid & 63;
    const int quad = lane >> 4, t = lane & 15;
    const int wr = wave >> 1, wc = wave & 1;

    f32x4_t acc[4][4] = {};

    const int lrow  = lane >> 2;
    const int lkoff = (((lane & 3) + (lane >> 3)) & 3) * 8;

    const __hip_bfloat16* Ag0 = A  + (m0 + wave * 32 +      lrow) * (long)K + lkoff;
    const __hip_bfloat16* Ag1 = A  + (m0 + wave * 32 + 16 + lrow) * (long)K + lkoff;
    const __hip_bfloat16* Bg0 = Bt + (long)(n0 + wave * 32 +      lrow) * K + lkoff;
    const __hip_bfloat16* Bg1 = Bt + (long)(n0 + wave * 32 + 16 + lrow) * K + lkoff;
    __hip_bfloat16* AsB0 = &As[(wave * 32) * 32];
    __hip_bfloat16* AsB1 = &As[(wave * 32 + 16) * 32];
    __hip_bfloat16* BsB0 = &Bs[(wave * 32) * 32];
    __hip_bfloat16* BsB1 = &Bs[(wave * 32 + 16) * 32];

    const int slot = ((quad - (t >> 1)) & 3) * 8;

    for (int k0 = 0; k0 < K; k0 += 32) {
        gld_lds16(Ag0 + k0, AsB0);
        gld_lds16(Ag1 + k0, AsB1);
        gld_lds16(Bg0 + k0, BsB0);
        gld_lds16(Bg1 + k0, BsB1);
        __syncthreads();
        bf16x8_t af[4], bfr[4];
        #pragma unroll
        for (int i = 0; i < 4; ++i)
            af[i] = *(const bf16x8_t*)&As[(wr * 64 + i * 16 + t) * 32 + slot];
        #pragma unroll
        for (int j = 0; j < 4; ++j)
            bfr[j] = *(const bf16x8_t*)&Bs[(wc * 64 + j * 16 + t) * 32 + slot];
        #pragma unroll
        for (int i = 0; i < 4; ++i)
            #pragma unroll
            for (int j = 0; j < 4; ++j)
                acc[i][j] = __builtin_amdgcn_mfma_f32_16x16x32_bf16(af[i], bfr[j], acc[i][j], 0, 0, 0);
        __syncthreads();
    }

    #pragma unroll
    for (int i = 0; i < 4; ++i) {
        const long rbase = m0 + wr * 64 + i * 16 + quad * 4;
        #pragma unroll
        for (int j = 0; j < 4; ++j) {
            const int col = n0 + wc * 64 + j * 16 + t;
            #pragma unroll
            for (int r = 0; r < 4; ++r) {
                float v = acc[i][j][r];
                if (epi == 1) {
                    v = fast_tanh(v + bias[col]);
                    ((__hip_bfloat16*)Cout)[(rbase + r) * 512 + col] = __float2bfloat16(v);
                } else if (epi == 2) {
                    ((__hip_bfloat16*)Cout)[(rbase + r) * 512 + col] = __float2bfloat16(v);
                } else if (epi == 3) {
                    const long m = rbase + r;
                    const int brow = (int)(m & 63);
                    const long idx =
                        ((((m >> 6) * 8 + (col >> 6)) * 16 + (brow >> 4) * 4 + ((col >> 4) & 3)) * 256)
                        + ((col >> 2) & 3) * 64 + (brow & 15) * 4 + (col & 3);
                    ((float*)Cout)[idx] = v;
                } else {
                    ((float*)Cout)[(rbase + r) * 512 + col] = v;
                }
            }
        }
    }
}

// ---------------- epilogue: tanh(acc) -> hs (XOR-swizzled), optional bias ----------------
__device__ inline void epi_store(
    __hip_bfloat16* hs, f32x4_t acc[4][4], const float* bias,
    int n0w, int quad, int t)
{
    #pragma unroll
    for (int j = 0; j < 4; ++j) {
        const int oc0 = n0w + j * 16 + quad * 4;     // 4 consecutive out cols
        float4 bl = {0.f, 0.f, 0.f, 0.f};
        if (bias) bl = *(const float4*)&bias[oc0];
        const int cbase = oc0 >> 3;
        const int sub = (quad & 1) * 4;
        #pragma unroll
        for (int rt = 0; rt < 4; ++rt) {
            const int row = rt * 16 + t;
            union { __hip_bfloat16 b[4]; uint2 v; } o;
            o.b[0] = __float2bfloat16(fast_tanh(acc[rt][j][0] + bl.x));
            o.b[1] = __float2bfloat16(fast_tanh(acc[rt][j][1] + bl.y));
            o.b[2] = __float2bfloat16(fast_tanh(acc[rt][j][2] + bl.z));
            o.b[3] = __float2bfloat16(fast_tanh(acc[rt][j][3] + bl.w));
            const int phys = (cbase & ~7) | ((cbase ^ (row & 7)) & 7);
            *(uint2*)&hs[row * 512 + phys * 8 + sub] = o.v;
        }
    }
}

// ---------------- fused MLP layer: hs(64x512) = tanh(hs @ W^T + bias) ----------------
// unroll 2 ONLY: unroll 4 makes the compiler pipeline wn/ac 4 deep -> spill
// (R11: WRITE_SIZE 56 -> 328 MB, fused 202 -> 282 us).
__device__ inline void mfma_layer(
    __hip_bfloat16* hs, const __hip_bfloat16* __restrict__ Wt,
    const float* __restrict__ bias, int w, int lane)
{
    const int quad = lane >> 4, t = lane & 15;
    const int n0w = w * 64;
    const __hip_bfloat16* Wl = Wt + ((size_t)(w * 4) * 16 * 64 + lane) * 8;
    f32x4_t acc[4][4] = {};   // [rt = batch tile][j = out tile]
    bf16x8_t wc[4], wn[4], ac[4];
    #pragma unroll
    for (int j = 0; j < 4; ++j)
        wc[j] = *(const bf16x8_t*)(Wl + (size_t)(j * 16) * 512);

    #pragma unroll 2
    for (int kc = 0; kc < 16; ++kc) {
        const int craw = kc * 4 + quad;
        const int phys = (craw & ~7) | ((craw ^ (t & 7)) & 7);
        #pragma unroll
        for (int rt = 0; rt < 4; ++rt)
            ac[rt] = *(const bf16x8_t*)&hs[(rt * 16 + t) * 512 + phys * 8];
        if (kc < 15) {
            #pragma unroll
            for (int j = 0; j < 4; ++j)
                wn[j] = *(const bf16x8_t*)(Wl + (size_t)(j * 16 + kc + 1) * 512);
        }
        #pragma unroll
        for (int j = 0; j < 4; ++j)
            #pragma unroll
            for (int rt = 0; rt < 4; ++rt)
                acc[rt][j] = __builtin_amdgcn_mfma_f32_16x16x32_bf16(wc[j], ac[rt], acc[rt][j], 0, 0, 0);
        #pragma unroll
        for (int j = 0; j < 4; ++j) wc[j] = wn[j];
    }
    __syncthreads();   // all reads of hs complete
    epi_store(hs, acc, bias, n0w, quad, t);
    __syncthreads();   // hs now holds the layer output
}

// ---------------- fused MLP kernel: q-blocks [0,2048), v-blocks [2048,2112) ----------------
__global__ __launch_bounds__(512, 4) void fused_kernel(
    const float* __restrict__ p,               // fragment-tiled fp32 = obs@W0a
    const float* __restrict__ pv,              // fragment-tiled fp32 = obs@vW0
    const __hip_bfloat16* __restrict__ acts_bf,// (131072,8) bf16 s-major
    const __hip_bfloat16* __restrict__ w0aug,  // tiled aug (32 tiles)
    const __hip_bfloat16* __restrict__ vw0aug,
    const __hip_bfloat16* __restrict__ w1t, const float* __restrict__ qb1,
    const __hip_bfloat16* __restrict__ w2t, const float* __restrict__ qb2,
    const __hip_bfloat16* __restrict__ w3t, const float* __restrict__ qb3,
    float* __restrict__ advout,
    const __hip_bfloat16* __restrict__ vw1t, const float* __restrict__ vb1,
    const __hip_bfloat16* __restrict__ vw2t, const float* __restrict__ vb2,
    const float* __restrict__ vw3, const float* __restrict__ vb3,
    float* __restrict__ vout)
{
    __shared__ __hip_bfloat16 hs[64 * 512];   // 64 KB
    const int bid = blockIdx.x;
    const int tid = threadIdx.x;
    const int w = tid >> 6, lane = tid & 63;
    const int quad = lane >> 4, t = lane & 15;
    const bool is_q = bid < 2048;
    const int s  = is_q ? (bid >> 6) : 0;
    const int mb = is_q ? (bid & 63) : (bid - 2048);
    const int n0w = w * 64;

    // ---- phase 0 as MFMA: D = W0aug·[acts;1] + p (acc init from tiled fp32 P) ----
    {
        const float* Pt = (is_q ? p : pv) + (((size_t)mb * 8 + w) * 16) * 256 + lane * 4;
        const __hip_bfloat16* W0 = is_q ? w0aug : vw0aug;
        f32x4_t acc[4][4];
        #pragma unroll
        for (int rt = 0; rt < 4; ++rt)
            #pragma unroll
            for (int j = 0; j < 4; ++j)
                acc[rt][j] = *(const f32x4_t*)(Pt + (rt * 4 + j) * 256);
        // B-frags: quad0 = acts (q only), quad1 = e0 1.0, else 0
        bf16x8_t bfrag[4];
        #pragma unroll
        for (int rt = 0; rt < 4; ++rt) {
            union { bf16x8_t vec; unsigned short u[8]; } bu;
            #pragma unroll
            for (int i = 0; i < 8; ++i) bu.u[i] = 0;
            if (quad == 1) bu.u[0] = 0x3F80;   // bf16 1.0
            if (is_q && quad == 0) {
                const long r = (long)s * 4096 + mb * 64 + rt * 16 + t;
                bu.vec = *(const bf16x8_t*)&acts_bf[r * 8];
            }
            bfrag[rt] = bu.vec;
        }
        bf16x8_t wq[4];
        #pragma unroll
        for (int j = 0; j < 4; ++j)
            wq[j] = *(const bf16x8_t*)(W0 + ((size_t)(w * 4 + j) * 64 + lane) * 8);
        #pragma unroll
        for (int j = 0; j < 4; ++j)
            #pragma unroll
            for (int rt = 0; rt < 4; ++rt)
                acc[rt][j] = __builtin_amdgcn_mfma_f32_16x16x32_bf16(wq[j], bfrag[rt], acc[rt][j], 0, 0, 0);
        epi_store(hs, acc, nullptr, n0w, quad, t);
    }
    __syncthreads();

    // ---- layers 1 and 2 ----
    mfma_layer(hs, is_q ? w1t : vw1t, is_q ? qb1 : vb1, w, lane);
    mfma_layer(hs, is_q ? w2t : vw2t, is_q ? qb2 : vb2, w, lane);

    // ---- layer 3 ----
    if (is_q) {
        // diag slice: 64 rows x 16 cols; waves 0..3 compute, output staged in LDS
        f32x4_t acc = {};
        if (w < 4) {
            const __hip_bfloat16* W3l = w3t + ((size_t)s * 16 * 64 + (size_t)lane) * 8;
            #pragma unroll 4
            for (int kc = 0; kc < 16; ++kc) {
                const int craw = kc * 4 + quad;
                const int phys = (craw & ~7) | ((craw ^ (t & 7)) & 7);
                bf16x8_t a = *(const bf16x8_t*)&hs[(w * 16 + t) * 512 + phys * 8];
                bf16x8_t bq = *(const bf16x8_t*)(W3l + (size_t)kc * 512);
                acc = __builtin_amdgcn_mfma_f32_16x16x32_bf16(a, bq, acc, 0, 0, 0);
            }
        }
        __syncthreads();   // L3 reads of hs done; hs reusable as fp32 staging
        float* hsf = (float*)hs;   // 64 rows x 16 cols
        if (w < 4) {
            const float bias3 = qb3[s * 16 + t];
            #pragma unroll
            for (int rr = 0; rr < 4; ++rr)
                hsf[(w * 16 + quad * 4 + rr) * 16 + t] = acc[rr] + bias3;
        }
        __syncthreads();
        // coalesced store: thread -> (row = tid>>3, colpair = tid&7), 64B/row
        const int row = tid >> 3, cp = tid & 7;
        float2 v2 = *(const float2*)&hsf[row * 16 + cp * 2];
        *(float2*)&advout[(size_t)(mb * 64 + row) * 512 + s * 16 + cp * 2] = v2;
    } else {
        // value head: row = tid>>3 (0..63), seg = tid&7 sums 64 elems
        const int row = tid >> 3, seg = tid & 7;
        float sum = 0.f;
        for (int k = seg * 64; k < seg * 64 + 64; ++k)
            sum += __bfloat162float(hs[hs_off(row, k)]) * vw3[k];
        sum += __shfl_xor(sum, 1);
        sum += __shfl_xor(sum, 2);
        sum += __shfl_xor(sum, 4);
        if (seg == 0) vout[mb * 64 + row] = sum + vb3[0];
    }
}

// ---------------- launch ----------------
extern "C" void kernel_launch(void* const* d_in, const int* in_sizes, int n_in,
                              void* d_out, int out_size, void* d_ws, size_t ws_size,
                              hipStream_t stream) {
    const float* obs      = (const float*)d_in[0];
    const int*   category = (const int*)d_in[1];
    const float* v_w0 = (const float*)d_in[2];
    const float* v_b0 = (const float*)d_in[3];
    const float* v_w1 = (const float*)d_in[4];
    const float* v_b1 = (const float*)d_in[5];
    const float* v_w2 = (const float*)d_in[6];
    const float* v_b2 = (const float*)d_in[7];
    const float* v_w3 = (const float*)d_in[8];
    const float* v_b3 = (const float*)d_in[9];
    const float* q_w0 = (const float*)d_in[10];
    const float* q_b0 = (const float*)d_in[11];
    const float* q_w1 = (const float*)d_in[12];
    const float* q_b1 = (const float*)d_in[13];
    const float* q_w2 = (const float*)d_in[14];
    const float* q_b2 = (const float*)d_in[15];
    const float* q_w3 = (const float*)d_in[16];
    const float* q_b3 = (const float*)d_in[17];

    char* ws = (char*)d_ws;
    __hip_bfloat16* obs_bf = (__hip_bfloat16*)(ws + 0);              // 1 MB
    __hip_bfloat16* w0t    = (__hip_bfloat16*)(ws + 1048576);        // (512,128) row-major
    __hip_bfloat16* vw0t   = (__hip_bfloat16*)(ws + 1179648);        // (512,128) row-major
    __hip_bfloat16* w1t    = (__hip_bfloat16*)(ws + 1310720);        // (512,512) tiled
    __hip_bfloat16* w2t    = (__hip_bfloat16*)(ws + 1835008);
    __hip_bfloat16* w3t    = (__hip_bfloat16*)(ws + 2359296);
    __hip_bfloat16* vw1t   = (__hip_bfloat16*)(ws + 2883584);
    __hip_bfloat16* vw2t   = (__hip_bfloat16*)(ws + 3407872);
    __hip_bfloat16* w0aug  = (__hip_bfloat16*)(ws + 3932160);        // 32 KB
    __hip_bfloat16* vw0aug = (__hip_bfloat16*)(ws + 3964928);        // 32 KB
    __hip_bfloat16* acts_bf= (__hip_bfloat16*)(ws + 3997696);        // (131072,8) bf16, 2 MB
    float*          p      = (float*)         (ws + 6094848);        // tiled fp32, 8 MB
    float*          pv     = (float*)         (ws + 14483456);       // tiled fp32, 8 MB

    float* out       = (float*)d_out;
    float* out_value = out;
    float* out_adv   = out + 4096;
    float* out_nbias = out + 4096 + (size_t)B_SZ * 512;

    // 1) all prep in one dispatch (incl. nbias zero)
    prep_kernel<<<12416, 256, 0, stream>>>(
        obs, category, q_w0, q_b0, q_w1, q_w2, q_w3, v_w0, v_b0, v_w1, v_w2,
        obs_bf, w0t, w1t, w2t, w3t, vw0t, vw1t, vw2t, w0aug, vw0aug,
        acts_bf, out_nbias);

    // 2) P: p = obs@W0a || pv = obs@vW0, fp32 fragment-tiled (epi=3)
    gemm_dual<<<256, 256, 0, stream>>>(
        obs_bf, w0t, nullptr, p, 128, 3, 128,
        obs_bf, vw0t, nullptr, pv, 128, 3);

    // 3) fused q+v MLP (2048 q-blocks + 64 v-blocks), 512 threads
    fused_kernel<<<2112, 512, 0, stream>>>(
        p, pv, acts_bf, w0aug, vw0aug, w1t, q_b1, w2t, q_b2, w3t, q_b3, out_adv,
        vw1t, v_b1, vw2t, v_b2, v_w3, v_b3, out_value);
}